// Round 8
// baseline (6376.973 us; speedup 1.0000x reference)
//
#include <hip/hip_runtime.h>

#define S_  2048
#define B_  8
#define CM_ 8192     // pass-1 chunk rows
#define KS_ 16       // all GEMMs have K=512 -> 16 k-slices of 32

typedef _Float16 f16x8 __attribute__((ext_vector_type(8)));
typedef float    f32x4 __attribute__((ext_vector_type(4)));

__device__ __forceinline__ float gelu_f(float x){
    return 0.5f * x * (1.0f + erff(x * 0.7071067811865476f));
}

// ---------------------------------------------------------------------------
// Frag-plane format, used for BOTH A (16-dim = rows) and B (16-dim = cols):
//   plane[((tile*KS + ks)*64 + l)*8 + j],  l = (k_octet<<4) | dim16_local,
//   k = ks*32 + (l>>4)*8 + j.   plane2 (residual*2048) at +planeStride.

// Weight prep: fp32 K×N row-major -> B-frag planes (dim16 = cols).
__global__ __launch_bounds__(256)
void prep_k(const float* __restrict__ src, _Float16* __restrict__ dst,
            int K, int N)
{
    int g = blockIdx.x * 256 + threadIdx.x;   // total = K*N/8
    int KS = K >> 5;
    int l  = g & 63;
    int rem = g >> 6;
    int ks = rem % KS;
    int fc = rem / KS;
    int kbase = ks * 32 + (l >> 4) * 8;
    int col   = fc * 16 + (l & 15);
    size_t KN = (size_t)K * N;
    #pragma unroll
    for (int j = 0; j < 8; j++) {
        float x = src[(size_t)(kbase + j) * N + col];
        _Float16 h1 = (_Float16)x;
        _Float16 h2 = (_Float16)((x - (float)h1) * 2048.0f);
        dst[(size_t)g * 8 + j]      = h1;
        dst[KN + (size_t)g * 8 + j] = h2;
    }
}

// hidden (B,S,H) fp32 -> A-frag planes, row gr = s*8+b  (16384 rows, K=512)
__global__ __launch_bounds__(256)
void prep_hidden_k(const float* __restrict__ hidden, _Float16* __restrict__ dst,
                   size_t PS)
{
    int g = blockIdx.x * 256 + threadIdx.x;   // total = 16384*512/8 = 1048576
    int l  = g & 63;
    int rem = g >> 6;
    int ks = rem & 15;
    int fr = rem >> 4;
    int gr = fr * 16 + (l & 15);
    int s = gr >> 3, b = gr & 7;
    int kbase = ks * 32 + (l >> 4) * 8;
    const float* src = hidden + ((size_t)b * S_ + s) * 512 + kbase;
    #pragma unroll
    for (int j = 0; j < 8; j++) {
        float x = src[j];
        _Float16 h1 = (_Float16)x;
        _Float16 h2 = (_Float16)((x - (float)h1) * 2048.0f);
        dst[(size_t)g * 8 + j]      = h1;
        dst[PS + (size_t)g * 8 + j] = h2;
    }
}

// ---------------------------------------------------------------------------
// Split-precision MFMA GEMM, K=512, BM=64, BN=128, 256 thr (4 waves 2x2).
// A and B read as frag planes directly from global. No LDS in main loop.
// EPI 0: C -> frag planes (C width always 512, KSc=16), optional PRED
// EPI 2: C -> f32 row-major partial (no bias/gelu)
// EPI 3: C -> f32 row-major finish (add prev + bias, gelu)
// AMAP 0: linear tiles (Ap pre-offset by caller)
// AMAP 2: beam gather (Ap = beamsF base; tiles decoded from r0+m0, sel)
// AMAP 3: depth-0 hidden gather (Ap = hiddenF base)
template<bool GELU, int EPI, int AMAP, bool PRED>
__global__ __launch_bounds__(256)
void fgemm(const _Float16* __restrict__ Ap, size_t aPS,
           const _Float16* __restrict__ Bp, size_t bPS, int fc0,
           const float* __restrict__ bias,
           _Float16* __restrict__ Cp, size_t cPS,
           float* __restrict__ Cf,
           const int* __restrict__ sel, int nsel, int r0)
{
    const int t    = threadIdx.x;
    const int m0   = blockIdx.x * 64;
    const int n0   = blockIdx.y * 128;
    const int lane = t & 63;
    const int wave = t >> 6;
    const int wr   = wave >> 1;
    const int wc   = wave & 1;

    // ---- A frag pointers (2 row-tiles per wave) ----
    const _Float16* ap[2];
    #pragma unroll
    for (int i = 0; i < 2; i++) {
        if (AMAP == 0) {
            int tl = (m0 >> 4) + wr * 2 + i;
            ap[i] = Ap + ((size_t)tl * KS_) * 512 + lane * 8;
        } else if (AMAP == 2) {
            int s = ((r0 + m0) >> 4) + wr * 2 + i;
            int j = (lane >> 3) & 1;
            int kb = sel[s * 2 + j] >> 2;
            int al = (lane & 48) | (kb << 3) | (lane & 7);
            ap[i] = Ap + ((size_t)s * KS_) * 512 + al * 8;
        } else {  // AMAP 3
            int s = ((r0 + m0) >> 4) + wr * 2 + i;
            int ti = s >> 1;
            int al = (lane & 48) | ((s & 1) << 3) | (lane & 7);
            ap[i] = Ap + ((size_t)ti * KS_) * 512 + al * 8;
        }
    }

    // ---- B frag pointers ----
    const _Float16* bjp[4];
    #pragma unroll
    for (int j = 0; j < 4; j++) {
        int fcg = fc0 + (n0 >> 4) + wc * 4 + j;
        bjp[j] = Bp + (size_t)fcg * KS_ * 512 + lane * 8;
    }

    f32x4 accM[2][4], accX[2][4];
    #pragma unroll
    for (int i = 0; i < 2; i++)
        #pragma unroll
        for (int j = 0; j < 4; j++) { accM[i][j] = (f32x4)0.0f; accX[i][j] = (f32x4)0.0f; }

    #pragma unroll 2
    for (int ks = 0; ks < KS_; ks++) {
        f16x8 a1[2], a2[2], b1[4], b2[4];
        #pragma unroll
        for (int i = 0; i < 2; i++) {
            a1[i] = *(const f16x8*)(ap[i] + (size_t)ks * 512);
            a2[i] = *(const f16x8*)(ap[i] + aPS + (size_t)ks * 512);
        }
        #pragma unroll
        for (int j = 0; j < 4; j++) {
            b1[j] = *(const f16x8*)(bjp[j] + (size_t)ks * 512);
            b2[j] = *(const f16x8*)(bjp[j] + bPS + (size_t)ks * 512);
        }
        #pragma unroll
        for (int i = 0; i < 2; i++)
            #pragma unroll
            for (int j = 0; j < 4; j++)
                accM[i][j] = __builtin_amdgcn_mfma_f32_16x16x32_f16(a1[i], b1[j], accM[i][j], 0, 0, 0);
        #pragma unroll
        for (int i = 0; i < 2; i++)
            #pragma unroll
            for (int j = 0; j < 4; j++)
                accX[i][j] = __builtin_amdgcn_mfma_f32_16x16x32_f16(a1[i], b2[j], accX[i][j], 0, 0, 0);
        #pragma unroll
        for (int i = 0; i < 2; i++)
            #pragma unroll
            for (int j = 0; j < 4; j++)
                accX[i][j] = __builtin_amdgcn_mfma_f32_16x16x32_f16(a2[i], b1[j], accX[i][j], 0, 0, 0);
    }

    const float inv2048 = 4.8828125e-4f;

    if (EPI == 2 || EPI == 3) {
        #pragma unroll
        for (int j = 0; j < 4; j++) {
            int lc = wc * 64 + j * 16 + (lane & 15);
            #pragma unroll
            for (int i = 0; i < 2; i++) {
                int lr = wr * 32 + i * 16 + ((lane >> 4) << 2);
                #pragma unroll
                for (int r = 0; r < 4; r++) {
                    float c = accM[i][j][r] + accX[i][j][r] * inv2048;
                    size_t idx = (size_t)(m0 + lr + r) * 512 + n0 + lc;
                    if (EPI == 3) {
                        c += Cf[idx] + bias[n0 + lc];
                        if (GELU) c = gelu_f(c);
                    }
                    Cf[idx] = c;
                }
            }
        }
        return;
    }

    // ---- EPI 0: frag-plane store via f16 LDS transpose (34.8 KB) ----
    __shared__ _Float16 sH1[64][136];
    __shared__ _Float16 sH2[64][136];
    #pragma unroll
    for (int j = 0; j < 4; j++) {
        int lc = wc * 64 + j * 16 + (lane & 15);
        float bv = bias[n0 + lc];
        #pragma unroll
        for (int i = 0; i < 2; i++) {
            int lr = wr * 32 + i * 16 + ((lane >> 4) << 2);
            #pragma unroll
            for (int r = 0; r < 4; r++) {
                float c = accM[i][j][r] + accX[i][j][r] * inv2048 + bv;
                if (GELU) c = gelu_f(c);
                _Float16 h1 = (_Float16)c;
                sH1[lr + r][lc] = h1;
                sH2[lr + r][lc] = (_Float16)((c - (float)h1) * 2048.0f);
            }
        }
    }
    __syncthreads();

    bool ok = true;
    if (PRED) {
        int prow = r0 + m0 + wave * 16 + (lane & 15);
        ok = ((sel[prow >> 3] & 3) == nsel);
    }
    if (ok) {
        int row = wave * 16 + (lane & 15);
        #pragma unroll
        for (int ksx = 0; ksx < 4; ksx++) {
            int coff = ksx * 32 + ((lane >> 4) << 3);
            f16x8 h1v = *(const f16x8*)&sH1[row][coff];
            f16x8 h2v = *(const f16x8*)&sH2[row][coff];
            size_t o = (((size_t)((m0 >> 4) + wave) * KS_) + (n0 >> 5) + ksx) * 512 + lane * 8;
            *(f16x8*)(Cp + o)       = h1v;
            *(f16x8*)(Cp + cPS + o) = h2v;
        }
    }
}

// ---------------------------------------------------------------------------
__global__ __launch_bounds__(256)
void score1_k(const float* __restrict__ h2, const float* __restrict__ We3,
              const float* __restrict__ be3, float* __restrict__ ev,
              int pr0, int n)
{
    int row  = blockIdx.x * 4 + (threadIdx.x >> 6);
    int lane = threadIdx.x & 63;
    const float* p = h2 + (size_t)row * 512;
    float s = 0.f;
    #pragma unroll
    for (int j = 0; j < 8; j++) s += p[lane + 64 * j] * We3[lane + 64 * j];
    #pragma unroll
    for (int off = 32; off > 0; off >>= 1) s += __shfl_down(s, off, 64);
    if (lane == 0) {
        int pr = pr0 + row;
        ev[(size_t)(pr >> 3) * 32 + n * 8 + (pr & 7)] = 1.0f / (1.0f + expf(-(s + be3[0])));
    }
}

__global__ __launch_bounds__(256)
void score2_k(const float* __restrict__ ev, float* __restrict__ sc, int n)
{
    int i = blockIdx.x * 256 + threadIdx.x;
    if (i >= n) return;
    float s = 0.f;
    #pragma unroll
    for (int b = 0; b < 8; b++) s += ev[i * 8 + b];
    sc[i] = (s * 0.125f) / 0.8f;
}

__global__ __launch_bounds__(256)
void select_k(const float* __restrict__ sc, int* __restrict__ sel, int K)
{
    int s = blockIdx.x * 256 + threadIdx.x;
    if (s >= S_) return;
    int K4 = K * 4;
    float cand[8];
    for (int k = 0; k < K; k++) {
        const float* scp = sc + (size_t)(s * K + k) * 4;
        bool keep[4] = {false, false, false, false};
        int count = 0;
        for (int i = 0; i < 4; i++) {
            float mind = INFINITY;
            for (int j = 0; j < 4; j++)
                if (keep[j]) mind = fminf(mind, fabsf(scp[i] - scp[j]));
            bool ki = ((count == 0) || (mind >= 0.1f)) && (count < 2);
            keep[i] = ki;
            if (ki) count++;
        }
        for (int i = 0; i < 4; i++) cand[k * 4 + i] = keep[i] ? scp[i] : -INFINITY;
    }
    int i0 = 0;
    for (int i = 1; i < K4; i++) if (cand[i] > cand[i0]) i0 = i;
    int i1 = -1;
    for (int i = 0; i < K4; i++) {
        if (i == i0) continue;
        if (i1 < 0 || cand[i] > cand[i1]) i1 = i;
    }
    if (!(cand[i1] > -INFINITY)) i1 = i0;
    sel[s * 2 + 0] = i0;
    sel[s * 2 + 1] = i1;
}

// out[b][s][:] = reconstruct(beamsF row 16s+b, j=0) + hidden[b][s][:]
__global__ __launch_bounds__(256)
void final_add_k(const _Float16* __restrict__ beamsF, size_t PS,
                 const float* __restrict__ hidden, float* __restrict__ out)
{
    int tid = blockIdx.x * 256 + threadIdx.x;   // total = 2048*8*64
    int oc = tid & 63;
    int rem = tid >> 6;
    int b = rem & 7;
    int s = rem >> 3;
    size_t o = (((size_t)s * KS_) + (oc >> 2)) * 512 + ((((oc & 3) << 4) | b) * 8);
    f16x8 m = *(const f16x8*)(beamsF + o);
    f16x8 x = *(const f16x8*)(beamsF + PS + o);
    const float* hp = hidden + ((size_t)b * S_ + s) * 512 + oc * 8;
    float* op = out + ((size_t)b * S_ + s) * 512 + oc * 8;
    #pragma unroll
    for (int j = 0; j < 8; j++)
        op[j] = (float)m[j] + (float)x[j] * 4.8828125e-4f + hp[j];
}

extern "C" void kernel_launch(void* const* d_in, const int* in_sizes, int n_in,
                              void* d_out, int out_size, void* d_ws, size_t ws_size,
                              hipStream_t stream)
{
    const float* hidden = (const float*)d_in[0];
    const float* We1 = (const float*)d_in[1];
    const float* be1 = (const float*)d_in[2];
    const float* We2 = (const float*)d_in[3];
    const float* be2 = (const float*)d_in[4];
    const float* We3 = (const float*)d_in[5];
    const float* be3 = (const float*)d_in[6];
    const float* Wp  = (const float*)d_in[7];
    const float* bp  = (const float*)d_in[8];
    const float* Wb  = (const float*)d_in[9];
    const float* bb  = (const float*)d_in[10];
    (void)in_sizes; (void)n_in; (void)ws_size;

    // ---- ws layout (f16 elems). total = 117.4 MB ----
    _Float16* beamsF = (_Float16*)d_ws;           // 2 planes x 16,777,216 (32768x512)
    const size_t PS_B = 16777216;
    _Float16* R1     = beamsF + 2 * PS_B;
    const size_t PS_C = 4194304;                  // 8192x512
    _Float16* projcF = R1;                        // 2*PS_C
    _Float16* thcF   = R1 + 2 * PS_C;             // 2*PS_C
    _Float16* h1hF   = R1 + 4 * PS_C;             // 2*PS_C
    const size_t PS_G = 8388608;                  // 16384x512 (pass-2 chunk)
    _Float16* projgF = R1;                        // reuses R1 (2*PS_G = 6*PS_C)

    // ---- d_out tail scratch (dead until final_add) ----
    float* outf = (float*)d_out;
    float* evb  = outf + (out_size - 131072);
    float* scb  = evb - 16384;
    int*   sel  = (int*)(scb - 4096);
    float* h2f  = (float*)sel - 4194304;          // 8192x512 f32
    _Float16* WpP  = (_Float16*)(h2f - 2359296);  // 4,718,592 f16 total:
    _Float16* WbP  = WpP + 524288;                //  Wp 524288 | Wb 4x524288
    _Float16* We1P = WbP + 2097152;               //  We1 1048576
    _Float16* We2Pa= We1P + 1048576;              //  We2 halves 524288 each
    _Float16* We2Pb= We2Pa + 524288;

    // ---- weight / hidden prep ----
    prep_k<<<128, 256, 0, stream>>>(Wp, WpP, 512, 512);
    for (int n = 0; n < 4; n++)
        prep_k<<<128, 256, 0, stream>>>(Wb + (size_t)n * 262144, WbP + (size_t)n * 524288, 512, 512);
    prep_k<<<256, 256, 0, stream>>>(We1, We1P, 512, 1024);
    prep_k<<<128, 256, 0, stream>>>(We2, We2Pa, 512, 512);
    prep_k<<<128, 256, 0, stream>>>(We2 + 262144, We2Pb, 512, 512);
    prep_hidden_k<<<4096, 256, 0, stream>>>(hidden, beamsF, PS_B);

    dim3 g1(128, 4), g2(256, 4);

    for (int d = 0; d < 3; d++) {
        const int K  = (d == 0) ? 1 : 2;
        const int NC = (d == 0) ? 2 : 4;

        // ---- pass 1: scores (chunked; states discarded) ----
        for (int c = 0; c < NC; c++) {
            size_t off = (size_t)c * CM_ * 512;
            fgemm<false, 0, 0, false><<<g1, 256, 0, stream>>>(
                beamsF + off, PS_B, WpP, 262144, 0, bp, projcF, PS_C, nullptr, nullptr, 0, 0);
            for (int n = 0; n < 4; n++) {
                fgemm<true, 0, 0, false><<<g1, 256, 0, stream>>>(
                    projcF, PS_C, WbP + (size_t)n * 524288, 262144, 0, bb + n * 512,
                    thcF, PS_C, nullptr, nullptr, 0, 0);
                for (int h = 0; h < 2; h++) {
                    fgemm<true, 0, 0, false><<<g1, 256, 0, stream>>>(
                        thcF, PS_C, We1P, 524288, h * 32, be1 + h * 512,
                        h1hF, PS_C, nullptr, nullptr, 0, 0);
                    if (h == 0)
                        fgemm<false, 2, 0, false><<<g1, 256, 0, stream>>>(
                            h1hF, PS_C, We2Pa, 262144, 0, nullptr, nullptr, 0, h2f, nullptr, 0, 0);
                    else
                        fgemm<true, 3, 0, false><<<g1, 256, 0, stream>>>(
                            h1hF, PS_C, We2Pb, 262144, 0, be2, nullptr, 0, h2f, nullptr, 0, 0);
                }
                score1_k<<<2048, 256, 0, stream>>>(h2f, We3, be3, evb, c * CM_, n);
            }
        }

        // ---- selection ----
        const int nsc = S_ * K * 4;
        score2_k<<<(nsc + 255) / 256, 256, 0, stream>>>(evb, scb, nsc);
        select_k<<<8, 256, 0, stream>>>(scb, sel, K);

        // ---- pass 2: recompute selected states.
        // Chunk order c2=1 then c2=0: at depth 0 the AMAP-3 source tiles for
        // chunk c2 live at rows [c2*8192, c2*8192+8191] of beamsF, and chunk
        // c2's predicated stores cover rows [c2*16384, ...]; reverse order
        // guarantees no chunk reads rows another chunk already overwrote. ----
        for (int cc = 0; cc < 2; cc++) {
            int c2 = 1 - cc;
            int r0 = c2 * 16384;
            if (d == 0)
                fgemm<false, 0, 3, false><<<g2, 256, 0, stream>>>(
                    beamsF, PS_B, WpP, 262144, 0, bp, projgF, PS_G, nullptr, sel, 0, r0);
            else
                fgemm<false, 0, 2, false><<<g2, 256, 0, stream>>>(
                    beamsF, PS_B, WpP, 262144, 0, bp, projgF, PS_G, nullptr, sel, 0, r0);
            for (int n = 0; n < 4; n++)
                fgemm<true, 0, 0, true><<<g2, 256, 0, stream>>>(
                    projgF, PS_G, WbP + (size_t)n * 524288, 262144, 0, bb + n * 512,
                    beamsF + (size_t)r0 * 512, PS_B, nullptr, sel, n, r0);
        }
    }

    final_add_k<<<4096, 256, 0, stream>>>(beamsF, PS_B, hidden, outf);
}

// Round 9
// 5542.232 us; speedup vs baseline: 1.1506x; 1.1506x over previous
//
#include <hip/hip_runtime.h>

#define S_  2048
#define B_  8
#define CM_ 8192     // pass-1 chunk rows

typedef _Float16 f16x8 __attribute__((ext_vector_type(8)));
typedef float    f32x4 __attribute__((ext_vector_type(4)));

__device__ __forceinline__ float gelu_f(float x){
    return 0.5f * x * (1.0f + erff(x * 0.7071067811865476f));
}

#define GLOAD_LDS(gp, lp) __builtin_amdgcn_global_load_lds( \
    (const __attribute__((address_space(1))) void*)(gp), \
    (__attribute__((address_space(3))) void*)(lp), 16, 0, 0)

// ---------------------------------------------------------------------------
// Frag-plane format (A: dim16=rows, B: dim16=cols):
//   plane[((tile*KS + ks)*64 + l)*8 + j],  l = (k_octet<<4) | dim16_local,
//   k = ks*32 + (l>>4)*8 + j.  plane2 (residual*2048) at +planeStride.

__global__ __launch_bounds__(256)
void prep_k(const float* __restrict__ src, _Float16* __restrict__ dst,
            int K, int N)
{
    int g = blockIdx.x * 256 + threadIdx.x;   // total = K*N/8
    int KS = K >> 5;
    int l  = g & 63;
    int rem = g >> 6;
    int ks = rem % KS;
    int fc = rem / KS;
    int kbase = ks * 32 + (l >> 4) * 8;
    int col   = fc * 16 + (l & 15);
    size_t KN = (size_t)K * N;
    #pragma unroll
    for (int j = 0; j < 8; j++) {
        float x = src[(size_t)(kbase + j) * N + col];
        _Float16 h1 = (_Float16)x;
        _Float16 h2 = (_Float16)((x - (float)h1) * 2048.0f);
        dst[(size_t)g * 8 + j]      = h1;
        dst[KN + (size_t)g * 8 + j] = h2;
    }
}

__global__ __launch_bounds__(256)
void prep_hidden_k(const float* __restrict__ hidden, _Float16* __restrict__ dst,
                   size_t PS)
{
    int g = blockIdx.x * 256 + threadIdx.x;   // total = 16384*512/8
    int l  = g & 63;
    int rem = g >> 6;
    int ks = rem & 15;
    int fr = rem >> 4;
    int gr = fr * 16 + (l & 15);
    int s = gr >> 3, b = gr & 7;
    int kbase = ks * 32 + (l >> 4) * 8;
    const float* src = hidden + ((size_t)b * S_ + s) * 512 + kbase;
    #pragma unroll
    for (int j = 0; j < 8; j++) {
        float x = src[j];
        _Float16 h1 = (_Float16)x;
        _Float16 h2 = (_Float16)((x - (float)h1) * 2048.0f);
        dst[(size_t)g * 8 + j]      = h1;
        dst[PS + (size_t)g * 8 + j] = h2;
    }
}

// ---------------------------------------------------------------------------
// Split-precision MFMA GEMM. BM=64, BN=64, 256 thr (4 waves 2x2, wave 32x32).
// A frags staged global->LDS via global_load_lds (async, double-buffered,
// 2 k-slices per step). B frags read from global (L2). K = KSN*32.
// Output: frag planes, C row width 512 per 32-col slice group, CKS slices.
// AMAP 0: linear tiles; 2: beam gather; 3: depth-0 hidden gather.
// PRED: store only rows whose sel[pair]&3 == nsel.
template<bool GELU, int KSN, int CKS, int AMAP, bool PRED>
__global__ __launch_bounds__(256, 4)
void fgemm(const _Float16* __restrict__ Ap, size_t aPS,
           const _Float16* __restrict__ Bp, size_t bPS,
           const float* __restrict__ bias,
           _Float16* __restrict__ Cp, size_t cPS,
           const int* __restrict__ sel, int nsel, int r0)
{
    __shared__ __align__(16) char smem[32768];
    const int t    = threadIdx.x;
    const int m0   = blockIdx.x * 64;
    const int n0   = blockIdx.y * 64;
    const int lane = t & 63;
    const int wave = t >> 6;
    const int wr   = wave >> 1;
    const int wc   = wave & 1;

    // ---- staging source for this wave's row-tile (tile index = wave) ----
    const _Float16* sap;
    {
        int i = wave;
        if (AMAP == 0) {
            int tl = (m0 >> 4) + i;
            sap = Ap + ((size_t)tl * KSN) * 512 + lane * 8;
        } else if (AMAP == 2) {
            int s = ((r0 + m0) >> 4) + i;
            int j = (lane >> 3) & 1;
            int kb = sel[s * 2 + j] >> 2;
            int al = (lane & 48) | (kb << 3) | (lane & 7);
            sap = Ap + ((size_t)s * KSN) * 512 + al * 8;
        } else {  // AMAP 3
            int s = ((r0 + m0) >> 4) + i;
            int ti = s >> 1;
            int al = (lane & 48) | ((s & 1) << 3) | (lane & 7);
            sap = Ap + ((size_t)ti * KSN) * 512 + al * 8;
        }
    }

    // ---- B frag pointers (2 col-tiles per wave) ----
    const _Float16* bjp[2];
    #pragma unroll
    for (int j = 0; j < 2; j++) {
        int fcg = (n0 >> 4) + wc * 2 + j;
        bjp[j] = Bp + (size_t)fcg * KSN * 512 + lane * 8;
    }

    f32x4 accM[2][2], accX[2][2];
    #pragma unroll
    for (int i = 0; i < 2; i++)
        #pragma unroll
        for (int j = 0; j < 2; j++) { accM[i][j] = (f32x4)0.0f; accX[i][j] = (f32x4)0.0f; }

    // stage pair p into buffer buf: wave stages its tile, 2 ks x 2 planes
    auto stage = [&](int buf, int p) {
        #pragma unroll
        for (int pl = 0; pl < 2; pl++)
            #pragma unroll
            for (int kk = 0; kk < 2; kk++) {
                const _Float16* g = sap + (size_t)(p * 2 + kk) * 512 + (size_t)pl * aPS;
                char* l = smem + ((((buf * 2 + pl) * 4 + wave) * 2) + kk) * 1024;
                GLOAD_LDS(g, l);
            }
    };

    const int NP = KSN / 2;
    stage(0, 0);
    __syncthreads();

    int buf = 0;
    for (int p = 0; p < NP; p++) {
        if (p + 1 < NP) stage(buf ^ 1, p + 1);
        #pragma unroll
        for (int kk = 0; kk < 2; kk++) {
            const int ks = p * 2 + kk;
            f16x8 b1[2], b2[2], a1[2], a2[2];
            #pragma unroll
            for (int j = 0; j < 2; j++) {
                b1[j] = *(const f16x8*)(bjp[j] + (size_t)ks * 512);
                b2[j] = *(const f16x8*)(bjp[j] + bPS + (size_t)ks * 512);
            }
            #pragma unroll
            for (int i = 0; i < 2; i++) {
                const char* l1 = smem + ((((buf * 2 + 0) * 4 + (wr * 2 + i)) * 2) + kk) * 1024 + lane * 16;
                const char* l2 = smem + ((((buf * 2 + 1) * 4 + (wr * 2 + i)) * 2) + kk) * 1024 + lane * 16;
                a1[i] = *(const f16x8*)l1;
                a2[i] = *(const f16x8*)l2;
            }
            #pragma unroll
            for (int i = 0; i < 2; i++)
                #pragma unroll
                for (int j = 0; j < 2; j++)
                    accM[i][j] = __builtin_amdgcn_mfma_f32_16x16x32_f16(a1[i], b1[j], accM[i][j], 0, 0, 0);
            #pragma unroll
            for (int i = 0; i < 2; i++)
                #pragma unroll
                for (int j = 0; j < 2; j++)
                    accX[i][j] = __builtin_amdgcn_mfma_f32_16x16x32_f16(a1[i], b2[j], accX[i][j], 0, 0, 0);
            #pragma unroll
            for (int i = 0; i < 2; i++)
                #pragma unroll
                for (int j = 0; j < 2; j++)
                    accX[i][j] = __builtin_amdgcn_mfma_f32_16x16x32_f16(a2[i], b1[j], accX[i][j], 0, 0, 0);
        }
        __syncthreads();
        buf ^= 1;
    }

    // ---- epilogue: frag-plane store via f16 LDS transpose (18.4 KB) ----
    const float inv2048 = 4.8828125e-4f;
    _Float16 (*sH1)[72] = (_Float16 (*)[72])smem;
    _Float16 (*sH2)[72] = (_Float16 (*)[72])(smem + 9216);
    #pragma unroll
    for (int j = 0; j < 2; j++) {
        int lc = wc * 32 + j * 16 + (lane & 15);
        float bv = bias[n0 + lc];
        #pragma unroll
        for (int i = 0; i < 2; i++) {
            int lr = wr * 32 + i * 16 + ((lane >> 4) << 2);
            #pragma unroll
            for (int r = 0; r < 4; r++) {
                float c = accM[i][j][r] + accX[i][j][r] * inv2048 + bv;
                if (GELU) c = gelu_f(c);
                _Float16 h1 = (_Float16)c;
                sH1[lr + r][lc] = h1;
                sH2[lr + r][lc] = (_Float16)((c - (float)h1) * 2048.0f);
            }
        }
    }
    __syncthreads();

    bool ok = true;
    if (PRED) ok = ((sel[(r0 + m0 + wave * 16 + (lane & 15)) >> 3] & 3) == nsel);
    if (ok) {
        int row = wave * 16 + (lane & 15);
        #pragma unroll
        for (int ksx = 0; ksx < 2; ksx++) {
            int coff = ksx * 32 + ((lane >> 4) << 3);
            f16x8 h1v = *(const f16x8*)&sH1[row][coff];
            f16x8 h2v = *(const f16x8*)&sH2[row][coff];
            size_t o = (((size_t)((m0 >> 4) + wave) * CKS) + (n0 >> 5) + ksx) * 512 + lane * 8;
            *(f16x8*)(Cp + o)       = h1v;
            *(f16x8*)(Cp + cPS + o) = h2v;
        }
    }
}

// ---------------------------------------------------------------------------
// score over frag-plane h2 (8192 rows x 512). One wave per row.
__global__ __launch_bounds__(256)
void score1f_k(const _Float16* __restrict__ h2F, size_t PS,
               const float* __restrict__ We3, const float* __restrict__ be3,
               float* __restrict__ ev, int pr0, int n)
{
    int row  = blockIdx.x * 4 + (threadIdx.x >> 6);
    int lane = threadIdx.x & 63;
    int tile = row >> 4, r16 = row & 15;
    size_t o = (((size_t)tile * 16 + (lane >> 2)) * 64 + (((lane & 3) << 4) | r16)) * 8;
    f16x8 m = *(const f16x8*)(h2F + o);
    f16x8 x = *(const f16x8*)(h2F + PS + o);
    int k0 = (lane >> 2) * 32 + (lane & 3) * 8;
    float s = 0.f;
    #pragma unroll
    for (int j = 0; j < 8; j++)
        s += ((float)m[j] + (float)x[j] * 4.8828125e-4f) * We3[k0 + j];
    #pragma unroll
    for (int off = 32; off > 0; off >>= 1) s += __shfl_down(s, off, 64);
    if (lane == 0) {
        int pr = pr0 + row;
        ev[(size_t)(pr >> 3) * 32 + n * 8 + (pr & 7)] = 1.0f / (1.0f + expf(-(s + be3[0])));
    }
}

__global__ __launch_bounds__(256)
void score2_k(const float* __restrict__ ev, float* __restrict__ sc, int n)
{
    int i = blockIdx.x * 256 + threadIdx.x;
    if (i >= n) return;
    float s = 0.f;
    #pragma unroll
    for (int b = 0; b < 8; b++) s += ev[i * 8 + b];
    sc[i] = (s * 0.125f) / 0.8f;
}

__global__ __launch_bounds__(256)
void select_k(const float* __restrict__ sc, int* __restrict__ sel, int K)
{
    int s = blockIdx.x * 256 + threadIdx.x;
    if (s >= S_) return;
    int K4 = K * 4;
    float cand[8];
    for (int k = 0; k < K; k++) {
        const float* scp = sc + (size_t)(s * K + k) * 4;
        bool keep[4] = {false, false, false, false};
        int count = 0;
        for (int i = 0; i < 4; i++) {
            float mind = INFINITY;
            for (int j = 0; j < 4; j++)
                if (keep[j]) mind = fminf(mind, fabsf(scp[i] - scp[j]));
            bool ki = ((count == 0) || (mind >= 0.1f)) && (count < 2);
            keep[i] = ki;
            if (ki) count++;
        }
        for (int i = 0; i < 4; i++) cand[k * 4 + i] = keep[i] ? scp[i] : -INFINITY;
    }
    int i0 = 0;
    for (int i = 1; i < K4; i++) if (cand[i] > cand[i0]) i0 = i;
    int i1 = -1;
    for (int i = 0; i < K4; i++) {
        if (i == i0) continue;
        if (i1 < 0 || cand[i] > cand[i1]) i1 = i;
    }
    if (!(cand[i1] > -INFINITY)) i1 = i0;
    sel[s * 2 + 0] = i0;
    sel[s * 2 + 1] = i1;
}

__global__ __launch_bounds__(256)
void final_add_k(const _Float16* __restrict__ beamsF, size_t PS,
                 const float* __restrict__ hidden, float* __restrict__ out)
{
    int tid = blockIdx.x * 256 + threadIdx.x;   // total = 2048*8*64
    int oc = tid & 63;
    int rem = tid >> 6;
    int b = rem & 7;
    int s = rem >> 3;
    size_t o = (((size_t)s * 16) + (oc >> 2)) * 512 + ((((oc & 3) << 4) | b) * 8);
    f16x8 m = *(const f16x8*)(beamsF + o);
    f16x8 x = *(const f16x8*)(beamsF + PS + o);
    const float* hp = hidden + ((size_t)b * S_ + s) * 512 + oc * 8;
    float* op = out + ((size_t)b * S_ + s) * 512 + oc * 8;
    #pragma unroll
    for (int j = 0; j < 8; j++)
        op[j] = (float)m[j] + (float)x[j] * 4.8828125e-4f + hp[j];
}

extern "C" void kernel_launch(void* const* d_in, const int* in_sizes, int n_in,
                              void* d_out, int out_size, void* d_ws, size_t ws_size,
                              hipStream_t stream)
{
    const float* hidden = (const float*)d_in[0];
    const float* We1 = (const float*)d_in[1];
    const float* be1 = (const float*)d_in[2];
    const float* We2 = (const float*)d_in[3];
    const float* be2 = (const float*)d_in[4];
    const float* We3 = (const float*)d_in[5];
    const float* be3 = (const float*)d_in[6];
    const float* Wp  = (const float*)d_in[7];
    const float* bp  = (const float*)d_in[8];
    const float* Wb  = (const float*)d_in[9];
    const float* bb  = (const float*)d_in[10];
    (void)in_sizes; (void)n_in; (void)ws_size;

    // ---- ws layout (f16 elems), 128 MB total ----
    _Float16* beamsF = (_Float16*)d_ws;            // 2 x 16,777,216 (32768x512)
    const size_t PS_B = 16777216;
    _Float16* R1     = beamsF + 2 * PS_B;          // 64 MB region
    const size_t PS_C = 4194304;                   // 8192x512
    const size_t PS_H = 8388608;                   // 8192x1024
    const size_t PS_G = 8388608;                   // 16384x512
    _Float16* projcF = R1;                         // 2*PS_C
    _Float16* thcF   = R1 + 2 * PS_C;              // 2*PS_C
    _Float16* h1F    = R1 + 4 * PS_C;              // 2*PS_H = 32MB
    _Float16* projgF = R1;                         // pass 2: 2*PS_G (reuses projc+thc)

    // ---- d_out tail scratch (dead until final_add) ----
    float* outf = (float*)d_out;
    float* evb  = outf + (out_size - 131072);
    float* scb  = evb - 16384;
    int*   sel  = (int*)(scb - 4096);
    _Float16* h2F = (_Float16*)((float*)sel - 4194304);  // 2*PS_C f16 = 16MB
    _Float16* WpP  = h2F - 4718592;               // weights: 9MB total
    _Float16* WbP  = WpP + 524288;
    _Float16* We1P = WbP + 2097152;
    _Float16* We2P = We1P + 1048576;

    // ---- weight / hidden prep ----
    prep_k<<<128, 256, 0, stream>>>(Wp, WpP, 512, 512);
    for (int n = 0; n < 4; n++)
        prep_k<<<128, 256, 0, stream>>>(Wb + (size_t)n * 262144, WbP + (size_t)n * 524288, 512, 512);
    prep_k<<<256, 256, 0, stream>>>(We1, We1P, 512, 1024);
    prep_k<<<256, 256, 0, stream>>>(We2, We2P, 1024, 512);
    prep_hidden_k<<<4096, 256, 0, stream>>>(hidden, beamsF, PS_B);

    dim3 gP(128, 8);    // M=8192,  N=512
    dim3 gW1(128, 16);  // M=8192,  N=1024
    dim3 gG(256, 8);    // M=16384, N=512

    for (int d = 0; d < 3; d++) {
        const int K  = (d == 0) ? 1 : 2;
        const int NC = (d == 0) ? 2 : 4;

        // ---- pass 1: scores (chunked; states discarded) ----
        for (int c = 0; c < NC; c++) {
            fgemm<false, 16, 16, 0, false><<<gP, 256, 0, stream>>>(
                beamsF + (size_t)c * CM_ * 512, PS_B, WpP, 262144, bp,
                projcF, PS_C, nullptr, 0, 0);
            for (int n = 0; n < 4; n++) {
                fgemm<true, 16, 16, 0, false><<<gP, 256, 0, stream>>>(
                    projcF, PS_C, WbP + (size_t)n * 524288, 262144, bb + n * 512,
                    thcF, PS_C, nullptr, 0, 0);
                fgemm<true, 16, 32, 0, false><<<gW1, 256, 0, stream>>>(
                    thcF, PS_C, We1P, 524288, be1,
                    h1F, PS_H, nullptr, 0, 0);
                fgemm<true, 32, 16, 0, false><<<gP, 256, 0, stream>>>(
                    h1F, PS_H, We2P, 524288, be2,
                    h2F, PS_C, nullptr, 0, 0);
                score1f_k<<<2048, 256, 0, stream>>>(h2F, PS_C, We3, be3, evb, c * CM_, n);
            }
        }

        // ---- selection ----
        const int nsc = S_ * K * 4;
        score2_k<<<(nsc + 255) / 256, 256, 0, stream>>>(evb, scb, nsc);
        select_k<<<8, 256, 0, stream>>>(scb, sel, K);

        // ---- pass 2: recompute selected states (chunks reversed: depth-0
        //      AMAP-3 sources for chunk c2 sit in rows [c2*8192, +8192) which
        //      chunk 0's stores would clobber if it ran first) ----
        for (int cc = 0; cc < 2; cc++) {
            int c2 = 1 - cc;
            int r0 = c2 * 16384;
            if (d == 0)
                fgemm<false, 16, 16, 3, false><<<gG, 256, 0, stream>>>(
                    beamsF, PS_B, WpP, 262144, bp, projgF, PS_G, sel, 0, r0);
            else
                fgemm<false, 16, 16, 2, false><<<gG, 256, 0, stream>>>(
                    beamsF, PS_B, WpP, 262144, bp, projgF, PS_G, sel, 0, r0);
            for (int n = 0; n < 4; n++)
                fgemm<true, 16, 16, 0, true><<<gG, 256, 0, stream>>>(
                    projgF, PS_G, WbP + (size_t)n * 524288, 262144, bb + n * 512,
                    beamsF + (size_t)r0 * 512, PS_B, sel, n, r0);
        }
    }

    final_add_k<<<4096, 256, 0, stream>>>(beamsF, PS_B, hidden, outf);
}